// Round 17
// baseline (596.386 us; speedup 1.0000x reference)
//
#include <hip/hip_runtime.h>
#include <stdint.h>

#define WW 48
#define NQ 2304             // 48*48
#define NWT 144             // (bh, qt) tiles of 256 queries
#define SCL 0.51011868f     // 8^-0.5 * log2(e)  (folded so softmax = exp2)
#define SHIFT 17.312340491f // 12 * log2(e)      (fixed-shift softmax)
#define ACCF (NWT * 2304)   // 331776 floats: ACC[wt][9][256]
#define QHF (16 * 48 * 2304)
// ws layout (floats): [0,ACCF) ACC | [ACCF, ACCF+QHF) QH

typedef float v2f __attribute__((ext_vector_type(2)));

__device__ __forceinline__ v2f v2fma(v2f a, v2f b, v2f c) {
    return __builtin_elementwise_fma(a, b, c);   // -> v_pk_fma_f32
}

// ---------------------------------------------------------------------------
// qh_pre: QH[bh][y2][n] = (q_n*SCL) . relh[y2 - y(n) + 47] - SHIFT
// Also zeroes this wt's ACC slab (folds the hipMemsetAsync dispatch;
// kernel-boundary L2 flush makes the zeros visible to attn's atomics).
// NO fences, NO counters (R16 lesson: per-block device fences serialize).
// ---------------------------------------------------------------------------
__global__ __launch_bounds__(256) void qh_pre(const float* __restrict__ in,
                                              const float* __restrict__ relh,
                                              float* __restrict__ QH,
                                              float* __restrict__ ACC) {
    const int bx = blockIdx.x;
    float* ab = ACC + (size_t)bx * 2304;
    for (int i = threadIdx.x; i < 2304; i += 256) ab[i] = 0.0f;

    const int bh = bx / 9;
    const int nt = bx - bh * 9;
    const int n = nt * 256 + threadIdx.x;
    const int b = bh >> 3, h = bh & 7;
    const int y = n / WW;

    const float* qp = in + ((size_t)(b * NQ + n) * 192 + h * 8);
    float4 a = *(const float4*)qp, bb = *(const float4*)(qp + 4);
    v2f Q0 = {a.x * SCL, a.y * SCL}, Q1 = {a.z * SCL, a.w * SCL};
    v2f Q2 = {bb.x * SCL, bb.y * SCL}, Q3 = {bb.z * SCL, bb.w * SCL};

    for (int y2 = 0; y2 < 48; ++y2) {
        const float* rh = relh + (y2 - y + 47) * 8;
        float4 ta = *(const float4*)rh, tb = *(const float4*)(rh + 4);
        v2f s = v2fma(Q0, (v2f){ta.x, ta.y},
                v2fma(Q1, (v2f){ta.z, ta.w},
                v2fma(Q2, (v2f){tb.x, tb.y},
                      Q3 * (v2f){tb.z, tb.w})));
        QH[(size_t)(bh * 48 + y2) * 2304 + n] = s.x + s.y - SHIFT;
    }
}

// ---------------------------------------------------------------------------
// attn: R15 engine (LDS-broadcast KV, 4 q/lane, packed fp32, precomputed QH,
// batched qh[4][8], XCD-local atomics — all measured-good) at FINER GRAIN:
// block = 2 waves = ONE kc chunk (3 key-cols), waves split rowhalves over
// the SAME 256-query tile. grid 2304 = 16 kc * 144 wt; bx = kc*144 + wt
// keeps all 16 contributors of a wt on one XCD (144 % 8 == 0).
// Identical total instruction/load/staging counts to R15 — only block
// granularity changes: 9 blocks/CU schedulable (was 4.5), finer tail,
// better cold-miss overlap. __launch_bounds__(128,4) = the proven 128-VGPR
// cap (R11 lesson: too-tight caps spill catastrophically).
// logit = q.k + q.rel_w[x2-x+47] + q.rel_h[y2-y+47]; p = exp2(logit'-SHIFT)
// ---------------------------------------------------------------------------
__global__ __launch_bounds__(128, 4) void attn_kernel(const float* __restrict__ in,
                                                      const float* __restrict__ relw,
                                                      const float* __restrict__ QH,
                                                      float* __restrict__ ACC) {
    __shared__ float4 lds[576];        // 9216 B: staging chunk, later merge buf

    const int bx = blockIdx.x;
    const int wt = bx % NWT;           // same-wt blocks share bx%8 -> same XCD
    const int kc = bx / NWT;           // 0..15 (3 columns each)
    const int bh = wt / 9;
    const int qt = wt - bh * 9;
    const int tid = threadIdx.x;
    const int lane = tid & 63;
    const int rowhalf = tid >> 6;      // 0..1
    const int b = bh >> 3, h = bh & 7;

    // ---- stage the block's chunk: 48 rows x 3 cols x [K|V] ----
    const float4* inp4 = (const float4*)in;
    for (int t = tid; t < 576; t += 128) {
        const int key = t >> 2, p = t & 3;
        const int row = key / 3, col = key - row * 3;
        const size_t px = (size_t)(b * NQ + row * 48 + kc * 3 + col) * 48;
        const int c4 = (p < 2) ? (16 + h * 2 + p) : (32 + h * 2 + (p - 2));
        lds[t] = inp4[px + c4];
    }

    // ---- this lane's four queries (packed fp32 pairs) ----
    v2f Q0[4], Q1[4], Q2[4], Q3[4];
    int xq[4];
#pragma unroll
    for (int j = 0; j < 4; ++j) {
        const int n = qt * 256 + j * 64 + lane;
        const int y = n / WW;
        xq[j] = n - y * WW;
        const float* qp = in + ((size_t)(b * NQ + n) * 192 + h * 8);
        float4 a = *(const float4*)qp, bb = *(const float4*)(qp + 4);
        Q0[j] = (v2f){a.x * SCL, a.y * SCL};
        Q1[j] = (v2f){a.z * SCL, a.w * SCL};
        Q2[j] = (v2f){bb.x * SCL, bb.y * SCL};
        Q3[j] = (v2f){bb.z * SCL, bb.w * SCL};
    }

    // ---- qw per (query, chunk column) from global relw ----
    float qw[4][3];
#pragma unroll
    for (int j = 0; j < 4; ++j)
#pragma unroll
        for (int c = 0; c < 3; ++c) {
            const float* rw = relw + (kc * 3 + c - xq[j] + 47) * 8;
            float4 ta = *(const float4*)rw, tb = *(const float4*)(rw + 4);
            v2f s = v2fma(Q0[j], (v2f){ta.x, ta.y},
                    v2fma(Q1[j], (v2f){ta.z, ta.w},
                    v2fma(Q2[j], (v2f){tb.x, tb.y},
                          Q3[j] * (v2f){tb.z, tb.w})));
            qw[j][c] = s.x + s.y;
        }

    __syncthreads();   // staged KV visible to both waves

    float l[4] = {0, 0, 0, 0};
    v2f A0[4], A1[4], A2[4], A3[4];
#pragma unroll
    for (int j = 0; j < 4; ++j) {
        A0[j] = (v2f){0.f, 0.f}; A1[j] = (v2f){0.f, 0.f};
        A2[j] = (v2f){0.f, 0.f}; A3[j] = (v2f){0.f, 0.f};
    }
    const float* myl = (const float*)lds;
    const float* qhbase = QH + (size_t)bh * 48 * 2304 + qt * 256 + lane;

#pragma unroll 1
    for (int R = 0; R < 3; ++R) {
        // ---- batch qh for this round's 8 rows (32-deep load-ahead) ----
        float qh[4][8];
#pragma unroll
        for (int row = 0; row < 8; ++row) {
            const int y2 = rowhalf * 24 + R * 8 + row;
            const float* qr = qhbase + (size_t)y2 * 2304;
#pragma unroll
            for (int j = 0; j < 4; ++j) qh[j][row] = qr[j * 64];
        }

#pragma unroll 2
        for (int row = 0; row < 8; ++row) {
            const int y2 = rowhalf * 24 + R * 8 + row;
#pragma unroll
            for (int c = 0; c < 3; ++c) {
                const int base = (y2 * 3 + c) * 16;     // wave-uniform
                const float4 k0 = *(const float4*)(myl + base);
                const float4 k1 = *(const float4*)(myl + base + 4);
                const float4 v0 = *(const float4*)(myl + base + 8);
                const float4 v1 = *(const float4*)(myl + base + 12);
                const v2f K0 = {k0.x, k0.y}, K1 = {k0.z, k0.w};
                const v2f K2 = {k1.x, k1.y}, K3 = {k1.z, k1.w};
                const v2f V0 = {v0.x, v0.y}, V1 = {v0.z, v0.w};
                const v2f V2 = {v1.x, v1.y}, V3 = {v1.z, v1.w};
#pragma unroll
                for (int j = 0; j < 4; ++j) {
                    v2f d = v2fma(Q0[j], K0,
                            v2fma(Q1[j], K1,
                            v2fma(Q2[j], K2, Q3[j] * K3)));
                    const float p = __builtin_amdgcn_exp2f(
                        (qh[j][row] + qw[j][c]) + (d.x + d.y));
                    l[j] += p;
                    const v2f pp = {p, p};
                    A0[j] = v2fma(pp, V0, A0[j]);
                    A1[j] = v2fma(pp, V1, A1[j]);
                    A2[j] = v2fma(pp, V2, A2[j]);
                    A3[j] = v2fma(pp, V3, A3[j]);
                }
            }
        }
    }

    // ---- two-phase in-block merge (reuse staging LDS) ----
    __syncthreads();   // both waves done reading staged KV
    float* mr = (float*)lds;           // [9][256] floats
    if (rowhalf == 0) {
#pragma unroll
        for (int j = 0; j < 4; ++j) {
            const int q = j * 64 + lane;
            mr[q] = l[j];
            mr[1 * 256 + q] = A0[j].x; mr[2 * 256 + q] = A0[j].y;
            mr[3 * 256 + q] = A1[j].x; mr[4 * 256 + q] = A1[j].y;
            mr[5 * 256 + q] = A2[j].x; mr[6 * 256 + q] = A2[j].y;
            mr[7 * 256 + q] = A3[j].x; mr[8 * 256 + q] = A3[j].y;
        }
    }
    __syncthreads();
    if (rowhalf == 1) {
#pragma unroll
        for (int j = 0; j < 4; ++j) {
            const int q = j * 64 + lane;
            mr[q] += l[j];
            mr[1 * 256 + q] += A0[j].x; mr[2 * 256 + q] += A0[j].y;
            mr[3 * 256 + q] += A1[j].x; mr[4 * 256 + q] += A1[j].y;
            mr[5 * 256 + q] += A2[j].x; mr[6 * 256 + q] += A2[j].y;
            mr[7 * 256 + q] += A3[j].x; mr[8 * 256 + q] += A3[j].y;
        }
    }
    __syncthreads();

    // ---- single atomic layer per block (XCD-local ACC lines) ----
    float* ab = ACC + (size_t)wt * 2304;
    for (int idx = tid; idx < 2304; idx += 128)
        atomicAdd(ab + idx, mr[idx]);
}

// ---------------------------------------------------------------------------
// normalize: read ACC, divide by l, write out[b][n][h*8+j]
// ---------------------------------------------------------------------------
__global__ __launch_bounds__(256) void norm_kernel(const float* __restrict__ ACC,
                                                   float* __restrict__ out) {
    const int t = blockIdx.x * 256 + threadIdx.x;   // [0, 36864)
    const int wt = t >> 8, q = t & 255;
    const float* ab = ACC + (size_t)wt * 2304;
    const float inv = 1.0f / ab[q];
    float s[8];
#pragma unroll
    for (int e = 0; e < 8; ++e) s[e] = ab[(1 + e) * 256 + q] * inv;
    const int bh = wt / 9;
    const int qtl = wt - bh * 9;
    const int n = qtl * 256 + q;
    const int b = bh >> 3, h = bh & 7;
    float* op = out + ((size_t)(b * NQ + n) * 64 + h * 8);
    ((float4*)op)[0] = make_float4(s[0], s[1], s[2], s[3]);
    ((float4*)op)[1] = make_float4(s[4], s[5], s[6], s[7]);
}

extern "C" void kernel_launch(void* const* d_in, const int* in_sizes, int n_in,
                              void* d_out, int out_size, void* d_ws, size_t ws_size,
                              hipStream_t stream) {
    const float* in   = (const float*)d_in[0];
    const float* relw = (const float*)d_in[1];
    const float* relh = (const float*)d_in[2];
    float* ACC = (float*)d_ws;                 // 1.33 MB
    float* QH  = (float*)d_ws + ACCF;          // 7.08 MB
    float* out = (float*)d_out;

    qh_pre<<<NWT, 256, 0, stream>>>(in, relh, QH, ACC);
    attn_kernel<<<16 * NWT, 128, 0, stream>>>(in, relw, QH, ACC);
    norm_kernel<<<NWT, 256, 0, stream>>>(ACC, out);
}

// Round 18
// 125.930 us; speedup vs baseline: 4.7359x; 4.7359x over previous
//
#include <hip/hip_runtime.h>
#include <stdint.h>

#define WW 48
#define NQ 2304             // 48*48
#define NWT 144             // (bh, qt) tiles of 256 queries
#define SCL 0.51011868f     // 8^-0.5 * log2(e)  (folded so softmax = exp2)
#define SHIFT 17.312340491f // 12 * log2(e)      (fixed-shift softmax)
#define ACCF (NWT * 2304)   // 331776 floats: ACC[wt][9][256]
#define QHF (16 * 48 * 2304)
// ws layout (floats): [0,ACCF) ACC | [ACCF, ACCF+QHF) QH

typedef float v2f __attribute__((ext_vector_type(2)));

__device__ __forceinline__ v2f v2fma(v2f a, v2f b, v2f c) {
    return __builtin_elementwise_fma(a, b, c);   // -> v_pk_fma_f32
}

// ---------------------------------------------------------------------------
// qh_pre: QH[bh][y2][n] = (q_n*SCL) . relh[y2 - y(n) + 47] - SHIFT
// Also zeroes this wt's ACC slab (folds the hipMemsetAsync dispatch —
// proven harmless in R16/R17). No fences/counters (R9/R16 lesson).
// ---------------------------------------------------------------------------
__global__ __launch_bounds__(256) void qh_pre(const float* __restrict__ in,
                                              const float* __restrict__ relh,
                                              float* __restrict__ QH,
                                              float* __restrict__ ACC) {
    const int bx = blockIdx.x;
    float* ab = ACC + (size_t)bx * 2304;
    for (int i = threadIdx.x; i < 2304; i += 256) ab[i] = 0.0f;

    const int bh = bx / 9;
    const int nt = bx - bh * 9;
    const int n = nt * 256 + threadIdx.x;
    const int b = bh >> 3, h = bh & 7;
    const int y = n / WW;

    const float* qp = in + ((size_t)(b * NQ + n) * 192 + h * 8);
    float4 a = *(const float4*)qp, bb = *(const float4*)(qp + 4);
    v2f Q0 = {a.x * SCL, a.y * SCL}, Q1 = {a.z * SCL, a.w * SCL};
    v2f Q2 = {bb.x * SCL, bb.y * SCL}, Q3 = {bb.z * SCL, bb.w * SCL};

    for (int y2 = 0; y2 < 48; ++y2) {
        const float* rh = relh + (y2 - y + 47) * 8;
        float4 ta = *(const float4*)rh, tb = *(const float4*)(rh + 4);
        v2f s = v2fma(Q0, (v2f){ta.x, ta.y},
                v2fma(Q1, (v2f){ta.z, ta.w},
                v2fma(Q2, (v2f){tb.x, tb.y},
                      Q3 * (v2f){tb.z, tb.w})));
        QH[(size_t)(bh * 48 + y2) * 2304 + n] = s.x + s.y - SHIFT;
    }
}

// ---------------------------------------------------------------------------
// attn: EXACT R15 kernel (measured best: 67.5us, VGPR 96, no spill).
// LDS-broadcast KV, 4 q/lane, packed fp32, precomputed QH (batched qh[4][8]),
// XCD-local atomic accumulation (bx = gg*144 + wt; 144%8==0 keeps all 8
// contributors of a wt on one XCD), two-phase in-block LDS merge, single
// atomic layer per block.
// __launch_bounds__(256,2) is LOAD-BEARING: the only budget that compiles
// this body spill-free (R11: (256,4)->64 VGPR->3.8GB scratch; R17:
// (128,4)->64 VGPR->1.8GB; R7: (192)->48 VGPR spill; R8: (64,1)->128 VGPR
// ok but 7.5% occupancy).
// logit = q.k + q.rel_w[x2-x+47] + q.rel_h[y2-y+47]; p = exp2(logit'-SHIFT)
// ---------------------------------------------------------------------------
__global__ __launch_bounds__(256, 2) void attn_kernel(const float* __restrict__ in,
                                                      const float* __restrict__ relw,
                                                      const float* __restrict__ QH,
                                                      float* __restrict__ ACC) {
    __shared__ float4 lds[1152];       // 18432 B: staging, later 2 merge regions

    const int bx = blockIdx.x;
    const int wt = bx % NWT;           // same-wt blocks share bx%8 -> same XCD
    const int gg = bx / NWT;           // 0..7
    const int bh = wt / 9;
    const int qt = wt - bh * 9;
    const int tid = threadIdx.x;
    const int lane = tid & 63;
    const int wv = tid >> 6;           // 0..3
    const int kc_local = wv >> 1;
    const int rowhalf = wv & 1;
    const int kc = gg * 2 + kc_local;  // 0..15 (3 columns each)
    const int b = bh >> 3, h = bh & 7;

    // ---- stage the block's 2 chunks: 48 rows x 3 cols x [K|V] each ----
    const float4* inp4 = (const float4*)in;
    for (int t = tid; t < 1152; t += 256) {
        const int chunk = t / 576, tt = t - chunk * 576;
        const int key = tt >> 2, p = tt & 3;
        const int row = key / 3, col = key - row * 3;
        const size_t px = (size_t)(b * NQ + row * 48 + (gg * 2 + chunk) * 3 + col) * 48;
        const int c4 = (p < 2) ? (16 + h * 2 + p) : (32 + h * 2 + (p - 2));
        lds[t] = inp4[px + c4];
    }

    // ---- this lane's four queries (packed fp32 pairs) ----
    v2f Q0[4], Q1[4], Q2[4], Q3[4];
    int xq[4];
#pragma unroll
    for (int j = 0; j < 4; ++j) {
        const int n = qt * 256 + j * 64 + lane;
        const int y = n / WW;
        xq[j] = n - y * WW;
        const float* qp = in + ((size_t)(b * NQ + n) * 192 + h * 8);
        float4 a = *(const float4*)qp, bb = *(const float4*)(qp + 4);
        Q0[j] = (v2f){a.x * SCL, a.y * SCL};
        Q1[j] = (v2f){a.z * SCL, a.w * SCL};
        Q2[j] = (v2f){bb.x * SCL, bb.y * SCL};
        Q3[j] = (v2f){bb.z * SCL, bb.w * SCL};
    }

    // ---- qw per (query, chunk column) from global relw ----
    float qw[4][3];
#pragma unroll
    for (int j = 0; j < 4; ++j)
#pragma unroll
        for (int c = 0; c < 3; ++c) {
            const float* rw = relw + (kc * 3 + c - xq[j] + 47) * 8;
            float4 ta = *(const float4*)rw, tb = *(const float4*)(rw + 4);
            v2f s = v2fma(Q0[j], (v2f){ta.x, ta.y},
                    v2fma(Q1[j], (v2f){ta.z, ta.w},
                    v2fma(Q2[j], (v2f){tb.x, tb.y},
                          Q3[j] * (v2f){tb.z, tb.w})));
            qw[j][c] = s.x + s.y;
        }

    __syncthreads();   // staged KV visible to the 2 waves sharing each chunk

    float l[4] = {0, 0, 0, 0};
    v2f A0[4], A1[4], A2[4], A3[4];
#pragma unroll
    for (int j = 0; j < 4; ++j) {
        A0[j] = (v2f){0.f, 0.f}; A1[j] = (v2f){0.f, 0.f};
        A2[j] = (v2f){0.f, 0.f}; A3[j] = (v2f){0.f, 0.f};
    }
    const float* myl = (const float*)(lds + kc_local * 576);
    const float* qhbase = QH + (size_t)bh * 48 * 2304 + qt * 256 + lane;

#pragma unroll 1
    for (int R = 0; R < 3; ++R) {
        // ---- qh for this round's 8 rows: coalesced dword loads ----
        float qh[4][8];
#pragma unroll
        for (int row = 0; row < 8; ++row) {
            const int y2 = rowhalf * 24 + R * 8 + row;
            const float* qr = qhbase + (size_t)y2 * 2304;
#pragma unroll
            for (int j = 0; j < 4; ++j) qh[j][row] = qr[j * 64];
        }

#pragma unroll 2
        for (int row = 0; row < 8; ++row) {
            const int y2 = rowhalf * 24 + R * 8 + row;
#pragma unroll
            for (int c = 0; c < 3; ++c) {
                const int base = (y2 * 3 + c) * 16;     // wave-uniform
                const float4 k0 = *(const float4*)(myl + base);
                const float4 k1 = *(const float4*)(myl + base + 4);
                const float4 v0 = *(const float4*)(myl + base + 8);
                const float4 v1 = *(const float4*)(myl + base + 12);
                const v2f K0 = {k0.x, k0.y}, K1 = {k0.z, k0.w};
                const v2f K2 = {k1.x, k1.y}, K3 = {k1.z, k1.w};
                const v2f V0 = {v0.x, v0.y}, V1 = {v0.z, v0.w};
                const v2f V2 = {v1.x, v1.y}, V3 = {v1.z, v1.w};
#pragma unroll
                for (int j = 0; j < 4; ++j) {
                    v2f d = v2fma(Q0[j], K0,
                            v2fma(Q1[j], K1,
                            v2fma(Q2[j], K2, Q3[j] * K3)));
                    const float p = __builtin_amdgcn_exp2f(
                        (qh[j][row] + qw[j][c]) + (d.x + d.y));
                    l[j] += p;
                    const v2f pp = {p, p};
                    A0[j] = v2fma(pp, V0, A0[j]);
                    A1[j] = v2fma(pp, V1, A1[j]);
                    A2[j] = v2fma(pp, V2, A2[j]);
                    A3[j] = v2fma(pp, V3, A3[j]);
                }
            }
        }
    }

    // ---- two-phase in-block merge (reuse staging LDS: 2 regions) ----
    __syncthreads();   // everyone done reading staged KV
    float* mr = (float*)(lds + kc_local * 576);   // region per wave-pair
    if (rowhalf == 0) {
#pragma unroll
        for (int j = 0; j < 4; ++j) {
            const int q = j * 64 + lane;
            mr[q] = l[j];
            mr[1 * 256 + q] = A0[j].x; mr[2 * 256 + q] = A0[j].y;
            mr[3 * 256 + q] = A1[j].x; mr[4 * 256 + q] = A1[j].y;
            mr[5 * 256 + q] = A2[j].x; mr[6 * 256 + q] = A2[j].y;
            mr[7 * 256 + q] = A3[j].x; mr[8 * 256 + q] = A3[j].y;
        }
    }
    __syncthreads();
    if (rowhalf == 1) {
#pragma unroll
        for (int j = 0; j < 4; ++j) {
            const int q = j * 64 + lane;
            mr[q] += l[j];
            mr[1 * 256 + q] += A0[j].x; mr[2 * 256 + q] += A0[j].y;
            mr[3 * 256 + q] += A1[j].x; mr[4 * 256 + q] += A1[j].y;
            mr[5 * 256 + q] += A2[j].x; mr[6 * 256 + q] += A2[j].y;
            mr[7 * 256 + q] += A3[j].x; mr[8 * 256 + q] += A3[j].y;
        }
    }
    __syncthreads();

    // ---- single atomic layer per block (XCD-local ACC lines) ----
    const float* r0 = (const float*)lds;
    const float* r1 = (const float*)(lds + 576);
    float* ab = ACC + (size_t)wt * 2304;
    for (int idx = tid; idx < 2304; idx += 256)
        atomicAdd(ab + idx, r0[idx] + r1[idx]);
}

// ---------------------------------------------------------------------------
// normalize: read ACC, divide by l, write out[b][n][h*8+j]
// ---------------------------------------------------------------------------
__global__ __launch_bounds__(256) void norm_kernel(const float* __restrict__ ACC,
                                                   float* __restrict__ out) {
    const int t = blockIdx.x * 256 + threadIdx.x;   // [0, 36864)
    const int wt = t >> 8, q = t & 255;
    const float* ab = ACC + (size_t)wt * 2304;
    const float inv = 1.0f / ab[q];
    float s[8];
#pragma unroll
    for (int e = 0; e < 8; ++e) s[e] = ab[(1 + e) * 256 + q] * inv;
    const int bh = wt / 9;
    const int qtl = wt - bh * 9;
    const int n = qtl * 256 + q;
    const int b = bh >> 3, h = bh & 7;
    float* op = out + ((size_t)(b * NQ + n) * 64 + h * 8);
    ((float4*)op)[0] = make_float4(s[0], s[1], s[2], s[3]);
    ((float4*)op)[1] = make_float4(s[4], s[5], s[6], s[7]);
}

extern "C" void kernel_launch(void* const* d_in, const int* in_sizes, int n_in,
                              void* d_out, int out_size, void* d_ws, size_t ws_size,
                              hipStream_t stream) {
    const float* in   = (const float*)d_in[0];
    const float* relw = (const float*)d_in[1];
    const float* relh = (const float*)d_in[2];
    float* ACC = (float*)d_ws;                 // 1.33 MB
    float* QH  = (float*)d_ws + ACCF;          // 7.08 MB
    float* out = (float*)d_out;

    qh_pre<<<NWT, 256, 0, stream>>>(in, relh, QH, ACC);
    attn_kernel<<<8 * NWT, 256, 0, stream>>>(in, relw, QH, ACC);
    norm_kernel<<<NWT, 256, 0, stream>>>(ACC, out);
}

// Round 19
// 123.262 us; speedup vs baseline: 4.8383x; 1.0216x over previous
//
#include <hip/hip_runtime.h>
#include <stdint.h>

#define WW 48
#define NQ 2304             // 48*48
#define NWT 144             // (bh, qt) tiles of 256 queries
#define SCL 0.51011868f     // 8^-0.5 * log2(e)  (folded so softmax = exp2)
#define SHIFT 17.312340491f // 12 * log2(e)      (fixed-shift softmax)
#define ACCF (NWT * 2304)   // 331776 floats: ACC[wt][9][256]
#define QHF (16 * 48 * 2304)
// ws layout (floats): [0,ACCF) ACC | [ACCF, ACCF+QHF) QH

typedef float v2f __attribute__((ext_vector_type(2)));

__device__ __forceinline__ v2f v2fma(v2f a, v2f b, v2f c) {
    return __builtin_elementwise_fma(a, b, c);   // -> v_pk_fma_f32
}

// ---------------------------------------------------------------------------
// qh_pre: QH[bh][y2][n] = (q_n*SCL) . relh[y2 - y(n) + 47] - SHIFT
// R19: re-gridded 144 -> 576 blocks (4 y2-segments x 144 wt) — R18's 144
// blocks = 0.56 blocks/CU was latency-bound at ~2 waves/CU. bx = seg*144+wt
// keeps bx%8 = wt%8 (144%8==0) so each wt's ACC zeroing + attn atomics stay
// on one XCD. Each seg-block zeroes its quarter of the wt slab.
// ---------------------------------------------------------------------------
__global__ __launch_bounds__(256) void qh_pre(const float* __restrict__ in,
                                              const float* __restrict__ relh,
                                              float* __restrict__ QH,
                                              float* __restrict__ ACC) {
    const int bx = blockIdx.x;
    const int seg = bx / NWT;          // 0..3
    const int wt = bx - seg * NWT;     // 0..143
    float* ab = ACC + (size_t)wt * 2304 + seg * 576;
    for (int i = threadIdx.x; i < 576; i += 256) ab[i] = 0.0f;

    const int bh = wt / 9;
    const int nt = wt - bh * 9;
    const int n = nt * 256 + threadIdx.x;
    const int b = bh >> 3, h = bh & 7;
    const int y = n / WW;

    const float* qp = in + ((size_t)(b * NQ + n) * 192 + h * 8);
    float4 a = *(const float4*)qp, bb = *(const float4*)(qp + 4);
    v2f Q0 = {a.x * SCL, a.y * SCL}, Q1 = {a.z * SCL, a.w * SCL};
    v2f Q2 = {bb.x * SCL, bb.y * SCL}, Q3 = {bb.z * SCL, bb.w * SCL};

    const int y2end = seg * 12 + 12;
    for (int y2 = seg * 12; y2 < y2end; ++y2) {
        const float* rh = relh + (y2 - y + 47) * 8;
        float4 ta = *(const float4*)rh, tb = *(const float4*)(rh + 4);
        v2f s = v2fma(Q0, (v2f){ta.x, ta.y},
                v2fma(Q1, (v2f){ta.z, ta.w},
                v2fma(Q2, (v2f){tb.x, tb.y},
                      Q3 * (v2f){tb.z, tb.w})));
        QH[(size_t)(bh * 48 + y2) * 2304 + n] = s.x + s.y - SHIFT;
    }
}

// ---------------------------------------------------------------------------
// attn: EXACT R15/R18 kernel (measured best: 67.5-68.6us, VGPR 96, no spill).
// LDS-broadcast KV, 4 q/lane, packed fp32, precomputed QH (batched qh[4][8]),
// XCD-local atomic accumulation (bx = gg*144 + wt; 144%8==0 keeps all 8
// contributors of a wt on one XCD), two-phase in-block LDS merge, single
// atomic layer per block.
// __launch_bounds__(256,2) is LOAD-BEARING: the only budget that compiles
// this body spill-free (R11: (256,4)->64 VGPR->3.8GB scratch; R17:
// (128,4)->64 VGPR->1.8GB; R7: (192)->48 VGPR spill; R8: (64,1)->128 VGPR
// ok but 7.5% occupancy).
// logit = q.k + q.rel_w[x2-x+47] + q.rel_h[y2-y+47]; p = exp2(logit'-SHIFT)
// ---------------------------------------------------------------------------
__global__ __launch_bounds__(256, 2) void attn_kernel(const float* __restrict__ in,
                                                      const float* __restrict__ relw,
                                                      const float* __restrict__ QH,
                                                      float* __restrict__ ACC) {
    __shared__ float4 lds[1152];       // 18432 B: staging, later 2 merge regions

    const int bx = blockIdx.x;
    const int wt = bx % NWT;           // same-wt blocks share bx%8 -> same XCD
    const int gg = bx / NWT;           // 0..7
    const int bh = wt / 9;
    const int qt = wt - bh * 9;
    const int tid = threadIdx.x;
    const int lane = tid & 63;
    const int wv = tid >> 6;           // 0..3
    const int kc_local = wv >> 1;
    const int rowhalf = wv & 1;
    const int kc = gg * 2 + kc_local;  // 0..15 (3 columns each)
    const int b = bh >> 3, h = bh & 7;

    // ---- stage the block's 2 chunks: 48 rows x 3 cols x [K|V] each ----
    const float4* inp4 = (const float4*)in;
    for (int t = tid; t < 1152; t += 256) {
        const int chunk = t / 576, tt = t - chunk * 576;
        const int key = tt >> 2, p = tt & 3;
        const int row = key / 3, col = key - row * 3;
        const size_t px = (size_t)(b * NQ + row * 48 + (gg * 2 + chunk) * 3 + col) * 48;
        const int c4 = (p < 2) ? (16 + h * 2 + p) : (32 + h * 2 + (p - 2));
        lds[t] = inp4[px + c4];
    }

    // ---- this lane's four queries (packed fp32 pairs) ----
    v2f Q0[4], Q1[4], Q2[4], Q3[4];
    int xq[4];
#pragma unroll
    for (int j = 0; j < 4; ++j) {
        const int n = qt * 256 + j * 64 + lane;
        const int y = n / WW;
        xq[j] = n - y * WW;
        const float* qp = in + ((size_t)(b * NQ + n) * 192 + h * 8);
        float4 a = *(const float4*)qp, bb = *(const float4*)(qp + 4);
        Q0[j] = (v2f){a.x * SCL, a.y * SCL};
        Q1[j] = (v2f){a.z * SCL, a.w * SCL};
        Q2[j] = (v2f){bb.x * SCL, bb.y * SCL};
        Q3[j] = (v2f){bb.z * SCL, bb.w * SCL};
    }

    // ---- qw per (query, chunk column) from global relw ----
    float qw[4][3];
#pragma unroll
    for (int j = 0; j < 4; ++j)
#pragma unroll
        for (int c = 0; c < 3; ++c) {
            const float* rw = relw + (kc * 3 + c - xq[j] + 47) * 8;
            float4 ta = *(const float4*)rw, tb = *(const float4*)(rw + 4);
            v2f s = v2fma(Q0[j], (v2f){ta.x, ta.y},
                    v2fma(Q1[j], (v2f){ta.z, ta.w},
                    v2fma(Q2[j], (v2f){tb.x, tb.y},
                          Q3[j] * (v2f){tb.z, tb.w})));
            qw[j][c] = s.x + s.y;
        }

    __syncthreads();   // staged KV visible to the 2 waves sharing each chunk

    float l[4] = {0, 0, 0, 0};
    v2f A0[4], A1[4], A2[4], A3[4];
#pragma unroll
    for (int j = 0; j < 4; ++j) {
        A0[j] = (v2f){0.f, 0.f}; A1[j] = (v2f){0.f, 0.f};
        A2[j] = (v2f){0.f, 0.f}; A3[j] = (v2f){0.f, 0.f};
    }
    const float* myl = (const float*)(lds + kc_local * 576);
    const float* qhbase = QH + (size_t)bh * 48 * 2304 + qt * 256 + lane;

#pragma unroll 1
    for (int R = 0; R < 3; ++R) {
        // ---- qh for this round's 8 rows: coalesced dword loads ----
        float qh[4][8];
#pragma unroll
        for (int row = 0; row < 8; ++row) {
            const int y2 = rowhalf * 24 + R * 8 + row;
            const float* qr = qhbase + (size_t)y2 * 2304;
#pragma unroll
            for (int j = 0; j < 4; ++j) qh[j][row] = qr[j * 64];
        }

#pragma unroll 2
        for (int row = 0; row < 8; ++row) {
            const int y2 = rowhalf * 24 + R * 8 + row;
#pragma unroll
            for (int c = 0; c < 3; ++c) {
                const int base = (y2 * 3 + c) * 16;     // wave-uniform
                const float4 k0 = *(const float4*)(myl + base);
                const float4 k1 = *(const float4*)(myl + base + 4);
                const float4 v0 = *(const float4*)(myl + base + 8);
                const float4 v1 = *(const float4*)(myl + base + 12);
                const v2f K0 = {k0.x, k0.y}, K1 = {k0.z, k0.w};
                const v2f K2 = {k1.x, k1.y}, K3 = {k1.z, k1.w};
                const v2f V0 = {v0.x, v0.y}, V1 = {v0.z, v0.w};
                const v2f V2 = {v1.x, v1.y}, V3 = {v1.z, v1.w};
#pragma unroll
                for (int j = 0; j < 4; ++j) {
                    v2f d = v2fma(Q0[j], K0,
                            v2fma(Q1[j], K1,
                            v2fma(Q2[j], K2, Q3[j] * K3)));
                    const float p = __builtin_amdgcn_exp2f(
                        (qh[j][row] + qw[j][c]) + (d.x + d.y));
                    l[j] += p;
                    const v2f pp = {p, p};
                    A0[j] = v2fma(pp, V0, A0[j]);
                    A1[j] = v2fma(pp, V1, A1[j]);
                    A2[j] = v2fma(pp, V2, A2[j]);
                    A3[j] = v2fma(pp, V3, A3[j]);
                }
            }
        }
    }

    // ---- two-phase in-block merge (reuse staging LDS: 2 regions) ----
    __syncthreads();   // everyone done reading staged KV
    float* mr = (float*)(lds + kc_local * 576);   // region per wave-pair
    if (rowhalf == 0) {
#pragma unroll
        for (int j = 0; j < 4; ++j) {
            const int q = j * 64 + lane;
            mr[q] = l[j];
            mr[1 * 256 + q] = A0[j].x; mr[2 * 256 + q] = A0[j].y;
            mr[3 * 256 + q] = A1[j].x; mr[4 * 256 + q] = A1[j].y;
            mr[5 * 256 + q] = A2[j].x; mr[6 * 256 + q] = A2[j].y;
            mr[7 * 256 + q] = A3[j].x; mr[8 * 256 + q] = A3[j].y;
        }
    }
    __syncthreads();
    if (rowhalf == 1) {
#pragma unroll
        for (int j = 0; j < 4; ++j) {
            const int q = j * 64 + lane;
            mr[q] += l[j];
            mr[1 * 256 + q] += A0[j].x; mr[2 * 256 + q] += A0[j].y;
            mr[3 * 256 + q] += A1[j].x; mr[4 * 256 + q] += A1[j].y;
            mr[5 * 256 + q] += A2[j].x; mr[6 * 256 + q] += A2[j].y;
            mr[7 * 256 + q] += A3[j].x; mr[8 * 256 + q] += A3[j].y;
        }
    }
    __syncthreads();

    // ---- single atomic layer per block (XCD-local ACC lines) ----
    const float* r0 = (const float*)lds;
    const float* r1 = (const float*)(lds + 576);
    float* ab = ACC + (size_t)wt * 2304;
    for (int idx = tid; idx < 2304; idx += 256)
        atomicAdd(ab + idx, r0[idx] + r1[idx]);
}

// ---------------------------------------------------------------------------
// normalize: read ACC, divide by l, write out[b][n][h*8+j]
// R19: 576 blocks x 64 threads (was 144 x 256) for 4x scheduling units.
// ---------------------------------------------------------------------------
__global__ __launch_bounds__(64) void norm_kernel(const float* __restrict__ ACC,
                                                  float* __restrict__ out) {
    const int bxx = blockIdx.x;
    const int wt = bxx >> 2;
    const int q = (bxx & 3) * 64 + threadIdx.x;
    const float* ab = ACC + (size_t)wt * 2304;
    const float inv = 1.0f / ab[q];
    float s[8];
#pragma unroll
    for (int e = 0; e < 8; ++e) s[e] = ab[(1 + e) * 256 + q] * inv;
    const int bh = wt / 9;
    const int qtl = wt - bh * 9;
    const int n = qtl * 256 + q;
    const int b = bh >> 3, h = bh & 7;
    float* op = out + ((size_t)(b * NQ + n) * 64 + h * 8);
    ((float4*)op)[0] = make_float4(s[0], s[1], s[2], s[3]);
    ((float4*)op)[1] = make_float4(s[4], s[5], s[6], s[7]);
}

extern "C" void kernel_launch(void* const* d_in, const int* in_sizes, int n_in,
                              void* d_out, int out_size, void* d_ws, size_t ws_size,
                              hipStream_t stream) {
    const float* in   = (const float*)d_in[0];
    const float* relw = (const float*)d_in[1];
    const float* relh = (const float*)d_in[2];
    float* ACC = (float*)d_ws;                 // 1.33 MB
    float* QH  = (float*)d_ws + ACCF;          // 7.08 MB
    float* out = (float*)d_out;

    qh_pre<<<4 * NWT, 256, 0, stream>>>(in, relh, QH, ACC);
    attn_kernel<<<8 * NWT, 256, 0, stream>>>(in, relw, QH, ACC);
    norm_kernel<<<4 * NWT, 64, 0, stream>>>(ACC, out);
}